// Round 3
// baseline (98.510 us; speedup 1.0000x reference)
//
#include <hip/hip_runtime.h>

// GALNLLLoss2d: fused 2x2 Cholesky-solve + log K1 Bessel NLL, mean-reduced.
// Inputs (f32): loc[B,2], m[B,2], L[B,2,2] (lower-tri, positive diag), x[B,2]
// Output: single f32 = -mean(log_prob)
// R3: single kernel (fixed-point int64 atomic finish), native rcp/log,
//     2-deep batched grid-stride loads for MLP.

#define C_LOG2   0.6931471805599453f
#define C_LOG2PI 1.8378770664093453f
#define C_LN2    0.69314718055994530942f
#define FXSCALE  4294967296.0   // 2^32 fixed-point scale for deterministic sum

__device__ __forceinline__ float fast_log(float v) {
    return __builtin_amdgcn_logf(v) * C_LN2;   // v_log_f32 is log2
}

__device__ __forceinline__ float gal_row(
    float lx, float ly, float mx, float my, float px, float py,
    float La, float Lb, float Lc)
{
    const float ia = __builtin_amdgcn_rcpf(La);
    const float ic = __builtin_amdgcn_rcpf(Lc);
    const float d0 = px - lx, d1 = py - ly;
    // y = L^{-1} v (forward substitution); v^T Sinv w = (L^{-1}v)·(L^{-1}w)
    const float ym0 = mx * ia;
    const float ym1 = (my - Lb * ym0) * ic;
    const float yx0 = d0 * ia;
    const float yx1 = (d1 - Lb * yx0) * ic;
    const float qm  = ym0 * ym0 + ym1 * ym1;   // m^T Sinv m
    const float qx  = yx0 * yx0 + yx1 * yx1;   // diff^T Sinv diff
    const float qxm = yx0 * ym0 + yx1 * ym1;   // diff^T Sinv m
    const float s = 2.0f + qm;
    const float z = sqrtf(s * qx);

    // Branchless A&S 9.8.3/9.8.7/9.8.8 with clamped safe args.
    const float zs = fminf(z, 2.0f);
    float t = zs * 0.26666666666f;  // z/3.75
    t = t * t;
    const float i1 = zs * (0.5f + t * (0.87890594f + t * (0.51498869f
                   + t * (0.15084934f + t * (0.02658733f + t * (0.00301532f
                   + t * 0.00032411f))))));
    const float t2 = zs * zs * 0.25f;
    const float zk1 = zs * fast_log(zs * 0.5f) * i1 + 1.0f + t2 * (0.15443144f
                    + t2 * (-0.67278579f + t2 * (-0.18156897f
                    + t2 * (-0.01919402f + t2 * (-0.00110404f
                    + t2 * (-0.00004686f))))));
    const float zl = fmaxf(z, 2.0f);
    const float u = 2.0f * __builtin_amdgcn_rcpf(zl);
    const float poly = 1.25331414f + u * (0.23498619f + u * (-0.03655620f
                     + u * (0.01504268f + u * (-0.00780353f + u * (0.00325614f
                     + u * (-0.00068245f))))));
    const bool small = (z <= 2.0f);
    // Fold: -log(a*c) + 0.5*log(qx/s) + log(kve1) - z
    //   small: = log( zk1 / (s*a*c) )                 [z/zs cancels]
    //   large: = log( poly*sqrt(z) / (s*a*c) ) - z
    const float arg = small ? zk1 : poly * sqrtf(z);
    const float tail = small ? 0.0f : z;
    return C_LOG2 + qxm - C_LOG2PI
         + fast_log(arg * __builtin_amdgcn_rcpf(s * La * Lc)) - tail;
}

__device__ __forceinline__ double gal_pair(
    const float4 l, const float4 mm, const float4 xx,
    const float4 LA, const float4 LB)
{
    const float r0 = gal_row(l.x, l.y, mm.x, mm.y, xx.x, xx.y, LA.x, LA.z, LA.w);
    const float r1 = gal_row(l.z, l.w, mm.z, mm.w, xx.z, xx.w, LB.x, LB.z, LB.w);
    return (double)r0 + (double)r1;
}

__global__ __launch_bounds__(256) void gal_main_kernel(
    const float4* __restrict__ loc4, const float4* __restrict__ m4,
    const float4* __restrict__ L4,   const float4* __restrict__ x4,
    long long* __restrict__ fxacc, int* __restrict__ counter,
    float* __restrict__ out, int npairs, double scale_out)
{
    double acc = 0.0;
    const int stride = gridDim.x * blockDim.x;
    const int tid = blockIdx.x * blockDim.x + threadIdx.x;
    for (int p = tid; p < npairs; p += 2 * stride) {
        const int p2 = p + stride;
        const bool has2 = p2 < npairs;
        const int ps = has2 ? p2 : p;
        // issue all 10 loads before any compute (MLP)
        const float4 l0 = loc4[p],  m0 = m4[p],  x0 = x4[p];
        const float4 A0 = L4[2 * p], B0 = L4[2 * p + 1];
        const float4 l1 = loc4[ps], m1 = m4[ps], x1 = x4[ps];
        const float4 A1 = L4[2 * ps], B1 = L4[2 * ps + 1];
        acc += gal_pair(l0, m0, x0, A0, B0);
        if (has2) acc += gal_pair(l1, m1, x1, A1, B1);
    }
    // wave64 down-reduce, then cross-wave via LDS
    #pragma unroll
    for (int off = 32; off > 0; off >>= 1)
        acc += __shfl_down(acc, off);
    __shared__ double smem[4];
    const int lane = threadIdx.x & 63;
    const int wid  = threadIdx.x >> 6;
    if (lane == 0) smem[wid] = acc;
    __syncthreads();
    if (threadIdx.x == 0) {
        const double bsum = smem[0] + smem[1] + smem[2] + smem[3];
        // deterministic: int64 adds are associative/commutative
        const long long q = (long long)llrint(bsum * FXSCALE);
        __hip_atomic_fetch_add(fxacc, q, __ATOMIC_RELAXED,
                               __HIP_MEMORY_SCOPE_AGENT);
        const int old = __hip_atomic_fetch_add(counter, 1, __ATOMIC_ACQ_REL,
                                               __HIP_MEMORY_SCOPE_AGENT);
        if (old == (int)gridDim.x - 1) {
            const long long tot = __hip_atomic_load(fxacc, __ATOMIC_RELAXED,
                                                    __HIP_MEMORY_SCOPE_AGENT);
            out[0] = (float)((double)tot * scale_out);
        }
    }
}

extern "C" void kernel_launch(void* const* d_in, const int* in_sizes, int n_in,
                              void* d_out, int out_size, void* d_ws, size_t ws_size,
                              hipStream_t stream) {
    const float* loc = (const float*)d_in[0];
    const float* m   = (const float*)d_in[1];
    const float* L   = (const float*)d_in[2];
    const float* x   = (const float*)d_in[3];
    const int n = in_sizes[0] / 2;       // B rows
    const int npairs = n / 2;

    long long* fxacc = (long long*)d_ws;
    int* counter = (int*)((char*)d_ws + sizeof(long long));
    hipMemsetAsync(d_ws, 0, 16, stream);  // zero accumulator + counter

    const int nblocks = 2048;  // 524288 threads; 4 pairs/thread (2 batched iters)
    const double scale_out = -1.0 / (FXSCALE * (double)n);
    gal_main_kernel<<<nblocks, 256, 0, stream>>>(
        (const float4*)loc, (const float4*)m, (const float4*)L,
        (const float4*)x, fxacc, counter, (float*)d_out, npairs, scale_out);
}

// Round 4
// 33.897 us; speedup vs baseline: 2.9062x; 2.9062x over previous
//
#include <hip/hip_runtime.h>

// GALNLLLoss2d: fused 2x2 Cholesky-solve + log K1 Bessel NLL, mean-reduced.
// Inputs (f32): loc[B,2], m[B,2], L[B,2,2] (lower-tri, positive diag), x[B,2]
// Output: single f32 = -mean(log_prob)
// R4: two-kernel deterministic reduce (R1 structure — R3's same-line block
//     atomics serialized cross-XCD, +60us), native v_rcp/v_log fast math,
//     2-deep unconditional load batching.

#define C_LOG2   0.6931471805599453f
#define C_LOG2PI 1.8378770664093453f
#define C_LN2    0.69314718055994530942f

__device__ __forceinline__ float fast_log(float v) {
    return __builtin_amdgcn_logf(v) * C_LN2;   // v_log_f32 is log2
}

__device__ __forceinline__ float gal_row(
    float2 l, float2 m, float2 x, float4 L)
{
    const float La = L.x, Lb = L.z, Lc = L.w;
    const float ia = __builtin_amdgcn_rcpf(La);
    const float ic = __builtin_amdgcn_rcpf(Lc);
    const float d0 = x.x - l.x, d1 = x.y - l.y;
    // y = L^{-1} v (forward substitution); v^T Sinv w = (L^{-1}v)·(L^{-1}w)
    const float ym0 = m.x * ia;
    const float ym1 = (m.y - Lb * ym0) * ic;
    const float yx0 = d0 * ia;
    const float yx1 = (d1 - Lb * yx0) * ic;
    const float qm  = ym0 * ym0 + ym1 * ym1;   // m^T Sinv m
    const float qx  = yx0 * yx0 + yx1 * yx1;   // diff^T Sinv diff
    const float qxm = yx0 * ym0 + yx1 * ym1;   // diff^T Sinv m
    const float s = 2.0f + qm;
    const float z = sqrtf(s * qx);

    // Branchless A&S 9.8.3/9.8.7/9.8.8 with clamped safe args.
    const float zs = fminf(z, 2.0f);
    float t = zs * 0.26666666666f;  // z/3.75
    t = t * t;
    const float i1 = zs * (0.5f + t * (0.87890594f + t * (0.51498869f
                   + t * (0.15084934f + t * (0.02658733f + t * (0.00301532f
                   + t * 0.00032411f))))));
    const float t2 = zs * zs * 0.25f;
    const float zk1 = zs * fast_log(zs * 0.5f) * i1 + 1.0f + t2 * (0.15443144f
                    + t2 * (-0.67278579f + t2 * (-0.18156897f
                    + t2 * (-0.01919402f + t2 * (-0.00110404f
                    + t2 * (-0.00004686f))))));
    const float zl = fmaxf(z, 2.0f);
    const float u = 2.0f * __builtin_amdgcn_rcpf(zl);
    const float poly = 1.25331414f + u * (0.23498619f + u * (-0.03655620f
                     + u * (0.01504268f + u * (-0.00780353f + u * (0.00325614f
                     + u * (-0.00068245f))))));
    const bool small = (z <= 2.0f);
    // Fold: -log(a*c) + 0.5*log(qx/s) + log(kve1) - z
    //   small: = log( zk1 / (s*a*c) )                 [z/zs cancels]
    //   large: = log( poly*sqrt(z) / (s*a*c) ) - z
    const float arg = small ? zk1 : poly * sqrtf(z);
    const float tail = small ? 0.0f : z;
    return C_LOG2 + qxm - C_LOG2PI
         + fast_log(arg * __builtin_amdgcn_rcpf(s * La * Lc)) - tail;
}

__global__ __launch_bounds__(256) void gal_main_kernel(
    const float2* __restrict__ loc2, const float2* __restrict__ m2,
    const float4* __restrict__ L4,   const float2* __restrict__ x2,
    double* __restrict__ partial, int n)
{
    double acc = 0.0;
    const int stride = gridDim.x * blockDim.x;
    int i = blockIdx.x * blockDim.x + threadIdx.x;
    // 2-deep unconditional batch: issue all 8 loads, then compute both rows.
    for (; i + stride < n; i += 2 * stride) {
        const int j = i + stride;
        const float2 l0 = loc2[i], mm0 = m2[i], xx0 = x2[i];
        const float4 A0 = L4[i];
        const float2 l1 = loc2[j], mm1 = m2[j], xx1 = x2[j];
        const float4 A1 = L4[j];
        acc += (double)gal_row(l0, mm0, xx0, A0);
        acc += (double)gal_row(l1, mm1, xx1, A1);
    }
    if (i < n)
        acc += (double)gal_row(loc2[i], m2[i], x2[i], L4[i]);

    // wave64 down-reduce, then cross-wave via LDS
    #pragma unroll
    for (int off = 32; off > 0; off >>= 1)
        acc += __shfl_down(acc, off);
    __shared__ double smem[4];
    const int lane = threadIdx.x & 63;
    const int wid  = threadIdx.x >> 6;
    if (lane == 0) smem[wid] = acc;
    __syncthreads();
    if (threadIdx.x == 0)
        partial[blockIdx.x] = smem[0] + smem[1] + smem[2] + smem[3];
}

__global__ __launch_bounds__(256) void gal_final_kernel(
    const double* __restrict__ partial, int nblocks,
    float* __restrict__ out, double inv_n)
{
    double acc = 0.0;
    for (int i = threadIdx.x; i < nblocks; i += 256)
        acc += partial[i];
    #pragma unroll
    for (int off = 32; off > 0; off >>= 1)
        acc += __shfl_down(acc, off);
    __shared__ double smem[4];
    const int lane = threadIdx.x & 63;
    const int wid  = threadIdx.x >> 6;
    if (lane == 0) smem[wid] = acc;
    __syncthreads();
    if (threadIdx.x == 0)
        out[0] = (float)(-(smem[0] + smem[1] + smem[2] + smem[3]) * inv_n);
}

extern "C" void kernel_launch(void* const* d_in, const int* in_sizes, int n_in,
                              void* d_out, int out_size, void* d_ws, size_t ws_size,
                              hipStream_t stream) {
    const float* loc = (const float*)d_in[0];
    const float* m   = (const float*)d_in[1];
    const float* L   = (const float*)d_in[2];
    const float* x   = (const float*)d_in[3];
    const int n = in_sizes[0] / 2;       // B rows

    int nblocks = 2048;  // 524288 threads = 8192 waves = full chip capacity
    const size_t need = (size_t)nblocks * sizeof(double);
    if (ws_size < need) nblocks = (int)(ws_size / sizeof(double));
    double* partial = (double*)d_ws;

    gal_main_kernel<<<nblocks, 256, 0, stream>>>(
        (const float2*)loc, (const float2*)m, (const float4*)L,
        (const float2*)x, partial, n);
    gal_final_kernel<<<1, 256, 0, stream>>>(partial, nblocks, (float*)d_out,
                                            1.0 / (double)n);
}